// Round 2
// baseline (329.339 us; speedup 1.0000x reference)
//
#include <hip/hip_runtime.h>
#include <math.h>

#define B_N 64
#define C_N 512
#define M_N 1024
#define K_W 2048  // W row: [H bf16 (1024) | X'=g*(h+pe) bf16 (1024)]

typedef __attribute__((ext_vector_type(8))) short bf16x8;
typedef __attribute__((ext_vector_type(4))) float f32x4;

__device__ __forceinline__ unsigned short f2b(float f) {
  unsigned int x = __builtin_bit_cast(unsigned int, f);
  unsigned int lsb = (x >> 16) & 1u;
  x += 0x7fffu + lsb;
  return (unsigned short)(x >> 16);
}

typedef __attribute__((address_space(1))) const unsigned int gas_uint;
typedef __attribute__((address_space(3))) unsigned int las_uint;
__device__ __forceinline__ void async_ld(const void* g, const void* l) {
  __builtin_amdgcn_global_load_lds((gas_uint*)(uintptr_t)g,
                                   (las_uint*)(unsigned int)(uintptr_t)l, 16, 0, 0);
}

// ---------- positional embedding fp32 [C][M] + fused per-row sums ----------
__global__ void k_pe(float* __restrict__ pe, float* __restrict__ pesum) {
  int c = blockIdx.x, m = threadIdx.x;  // 512 blocks x 1024 threads
  float freq = expf((float)(c & ~1) * (-9.210340371976184f / 512.0f));
  float ang = (float)m * freq;
  float v = (c & 1) ? cosf(ang) : sinf(ang);
  pe[c * M_N + m] = v;
  float s = v;
  for (int off = 32; off; off >>= 1) s += __shfl_down(s, off);
  __shared__ float ws[16];
  if ((m & 63) == 0) ws[m >> 6] = s;
  __syncthreads();
  if (m < 16) {
    float t = ws[m];
    for (int off = 8; off; off >>= 1) t += __shfl_down(t, off);
    if (m == 0) pesum[c] = t;
  }
}

// ---------- pass 1: fp32 row sums (one atomic per wave; wave = half row) ----
__global__ void k_rs(const float* __restrict__ src, float* __restrict__ rb) {
  size_t e = ((size_t)blockIdx.x * 256 + threadIdx.x) * 8;
  const float4* s4 = (const float4*)(src + e);
  float4 v0 = s4[0], v1 = s4[1];
  float s = v0.x + v0.y + v0.z + v0.w + v1.x + v1.y + v1.z + v1.w;
  for (int off = 32; off; off >>= 1) s += __shfl_down(s, off);
  if ((threadIdx.x & 63) == 0) atomicAdd(&rb[e >> 10], s);
}

// ---------- gate (fp32 exact): outputs u = g*(rb+pesum), rb copy, g ----------
__global__ void k_gate(const float* __restrict__ wp, const float* __restrict__ bp,
                       const float* __restrict__ rb0, const float* __restrict__ pesum,
                       float* __restrict__ u, float* __restrict__ rbF,
                       float* __restrict__ gateF) {
  int idx = blockIdx.x * 256 + threadIdx.x;  // [0, B*C)
  int b = idx >> 9, c = idx & (C_N - 1);
  float rbv = rb0[idx];
  float rx = rbv + pesum[c];
  float acc = 0.f;
  for (int k = 0; k < 5; ++k) {
    int cc = c + k - 2;
    if (cc < 0 || cc >= C_N) continue;
    float y = (rb0[b * C_N + cc] + pesum[cc]) * (1.0f / 1024.0f);
    acc += y * wp[c * 5 + k];
  }
  float g = 1.0f / (1.0f + expf(-(acc + bp[c])));
  gateF[idx] = g;
  u[idx] = g * rx;
  rbF[idx] = rbv;
}

// ---------- pass 2: IN-PLACE fp32 row -> [H bf16 | X' bf16] -----------------
// One block per (b,c) row: read whole row (+pe row) -> barrier -> overwrite.
__global__ void k_x(float* __restrict__ hbase, const float* __restrict__ pe,
                    const float* __restrict__ gateF) {
  int row = blockIdx.x;  // b*512 + c
  int c = row & (C_N - 1), t = threadIdx.x;
  float* rp = hbase + (size_t)row * M_N;
  float4 h4 = ((const float4*)rp)[t];
  float4 p4 = ((const float4*)(pe + (size_t)c * M_N))[t];
  float g = gateF[row];
  union { uint2 v; unsigned short us[4]; } H, X;
  H.us[0] = f2b(h4.x); H.us[1] = f2b(h4.y); H.us[2] = f2b(h4.z); H.us[3] = f2b(h4.w);
  X.us[0] = f2b(g * (h4.x + p4.x)); X.us[1] = f2b(g * (h4.y + p4.y));
  X.us[2] = f2b(g * (h4.z + p4.z)); X.us[3] = f2b(g * (h4.w + p4.w));
  __syncthreads();  // all reads of this row complete before any write
  unsigned short* wr = (unsigned short*)rp;
  ((uint2*)wr)[t] = H.v;            // H half: shorts [0,1024)
  ((uint2*)(wr + M_N))[t] = X.v;    // X' half: shorts [1024,2048)
}

// ---------- cov: per-batch SYRK  out = (W W^T)/M - (u u^T + rb rb^T)/M^2 ----
// Depth-3 counted-vmcnt pipeline (T3+T4+T5): 4 LDS buffers, stage(it+3) in
// flight while computing buf[it&3]; vmcnt never drained to 0 in main loop.
// Per-iteration: vmcnt(8) -> s_barrier -> ds_read + stage issue -> lgkmcnt(0)
// -> setprio(1) + 16 MFMA. sched_barrier(0) pins motion at every wait point.
__device__ __forceinline__ void cov_stage(unsigned short (*tl)[128 * 32],
                                          const unsigned short* srcp, int wsel,
                                          int ldst) {
  for (int g = 0; g < 4; g++)
    async_ld(srcp + (size_t)g * (16 * K_W), &tl[wsel][ldst + g * 512]);
}

template <int VM, bool STG>
__device__ __forceinline__ void cov_step(
    unsigned short (*tiles)[2][128 * 32], int it, const unsigned short* srcp,
    int wsel, int ldst, int wr, int wc, int fr, int fcol, f32x4 (&acc)[4][4]) {
  asm volatile("s_waitcnt vmcnt(%0)" ::"n"(VM) : "memory");
  __builtin_amdgcn_sched_barrier(0);
  __builtin_amdgcn_s_barrier();
  __builtin_amdgcn_sched_barrier(0);
  int cur = it & 3;
  bf16x8 bf[4], af[4];
  for (int j = 0; j < 4; j++)
    bf[j] = *(const bf16x8*)&tiles[cur][1][(wc + j * 16 + fr) * 32 + fcol];
  for (int i = 0; i < 4; i++)
    af[i] = *(const bf16x8*)&tiles[cur][0][(wr + i * 16 + fr) * 32 + fcol];
  if (STG) cov_stage(tiles[(it + 3) & 3], srcp + (size_t)(it + 3) * 32, wsel, ldst);
  asm volatile("s_waitcnt lgkmcnt(0)" ::: "memory");
  __builtin_amdgcn_sched_barrier(0);
  __builtin_amdgcn_s_setprio(1);
  for (int i = 0; i < 4; i++)
    for (int j = 0; j < 4; j++)
      acc[i][j] = __builtin_amdgcn_mfma_f32_16x16x32_bf16(af[i], bf[j], acc[i][j], 0, 0, 0);
  __builtin_amdgcn_s_setprio(0);
}

__global__ __launch_bounds__(256, 2)
void k_cov(const unsigned short* __restrict__ W, const float* __restrict__ aux,
           float* __restrict__ out, int b0) {
  __shared__ unsigned short tiles[4][2][128 * 32];  // 4 bufs x (A,B) = 64 KB
  int t = threadIdx.x, lane = t & 63, w = t >> 6;
  int bid = blockIdx.x;
  int xcd = bid & 7, i5 = bid >> 3;
  int b = b0 + xcd * 4 + (i5 >> 4);
  int s = i5 & 15;
  int cblk = (s >> 2) * 128, dblk = (s & 3) * 128;

  int rowbase = (w & 1) ? dblk : cblk;
  int half = w >> 1, wsel = w & 1;
  int gcol = (lane & 3) ^ ((lane >> 3) & 3);
  const unsigned short* srcp = W + (size_t)b * (C_N * K_W)
      + (size_t)(rowbase + half * 64 + (lane >> 2)) * K_W + gcol * 8;
  int ldst = half * 2048;

  int wr = (w >> 1) * 64, wc = (w & 1) * 64;
  int fr = lane & 15, kc = lane >> 4;
  int fcol = (kc ^ ((fr >> 1) & 3)) * 8;

  f32x4 acc[4][4];
  const f32x4 z = {0.f, 0.f, 0.f, 0.f};
  for (int i = 0; i < 4; i++) for (int j = 0; j < 4; j++) acc[i][j] = z;

  // prologue: stage k-steps 0,1,2 into bufs 0,1,2 (12 loads in flight)
  for (int s0 = 0; s0 < 3; ++s0)
    cov_stage(tiles[s0], srcp + (size_t)s0 * 32, wsel, ldst);

  for (int it = 0; it < 61; ++it)  // issues stages 3..63
    cov_step<8, true>(tiles, it, srcp, wsel, ldst, wr, wc, fr, fcol, acc);
  cov_step<8, false>(tiles, 61, srcp, wsel, ldst, wr, wc, fr, fcol, acc);
  cov_step<4, false>(tiles, 62, srcp, wsel, ldst, wr, wc, fr, fcol, acc);
  cov_step<0, false>(tiles, 63, srcp, wsel, ldst, wr, wc, fr, fcol, acc);

  const float invM = 1.0f / 1024.0f, invM2 = invM * invM;
  const float* ub = aux + (size_t)b * C_N;
  const float* rbb = aux + (size_t)B_N * C_N + (size_t)b * C_N;
  for (int i = 0; i < 4; i++)
    for (int r = 0; r < 4; r++) {
      int c = cblk + wr + i * 16 + kc * 4 + r;
      float uc = ub[c], rbc = rbb[c];
      for (int j = 0; j < 4; j++) {
        int d = dblk + wc + j * 16 + fr;
        float v = acc[i][j][r] * invM - (uc * ub[d] + rbc * rbb[d]) * invM2;
        if (c == d) v += 1e-8f;
        out[((size_t)b * C_N + c) * C_N + d] = v;
      }
    }
}

extern "C" void kernel_launch(void* const* d_in, const int* in_sizes, int n_in,
                              void* d_out, int out_size, void* d_ws, size_t ws_size,
                              hipStream_t stream) {
  const float* h32 = (const float*)d_in[0];
  const float* conv_w = (const float*)d_in[1];
  const float* conv_b = (const float*)d_in[2];
  char* OUT = (char*)d_out;   // 64 MiB output; [48,52) MiB = scratch until covL2
  char* HIN = (char*)d_in[0]; // 128 MiB input; becomes W in-place (harness restores)

  // aux in OUT at batch-48 region: covL1 (b 0..31) never writes there.
  char* AUXA = OUT + (48ull << 20);
  float* uA    = (float*)(AUXA);                 // 128 KiB: u = g*(rb+pesum)
  float* rbA   = (float*)(AUXA + (128 << 10));   // 128 KiB: rb
  float* gateF = (float*)(AUXA + (256 << 10));   // 128 KiB
  float* rb0   = (float*)(AUXA + (384 << 10));   // 128 KiB atomic accum
  float* pesum = (float*)(AUXA + (512 << 10));   // 2 KiB
  float* peF   = (float*)(OUT + (49ull << 20));  // 2 MiB fp32 pe table
  char* AUXB = HIN;  // dead W region of batch 0 after covL1

  hipMemsetAsync(rb0, 0, 128 << 10, stream);
  k_pe<<<C_N, 1024, 0, stream>>>(peF, pesum);
  k_rs<<<16384, 256, 0, stream>>>(h32, rb0);
  k_gate<<<(B_N * C_N) / 256, 256, 0, stream>>>(conv_w, conv_b, rb0, pesum,
                                                uA, rbA, gateF);
  k_x<<<B_N * C_N, 256, 0, stream>>>((float*)HIN, peF, gateF);

  // covL1: batches 0..31 -> OUT[0,32MiB), aux from OUT+48MiB
  k_cov<<<512, 256, 0, stream>>>((const unsigned short*)HIN, uA, (float*)d_out, 0);
  // move aux into dead W(b=0) region, then covL2 overwrites OUT[32,64)
  hipMemcpyAsync(AUXB, AUXA, 256 << 10, hipMemcpyDeviceToDevice, stream);
  k_cov<<<512, 256, 0, stream>>>((const unsigned short*)HIN, (const float*)AUXB,
                                 (float*)d_out, 32);
}

// Round 3
// 300.291 us; speedup vs baseline: 1.0967x; 1.0967x over previous
//
#include <hip/hip_runtime.h>
#include <math.h>

#define B_N 64
#define C_N 512
#define M_N 1024
#define K_W 2048  // W row: [H bf16 (1024) | X'=g*(h+pe) bf16 (1024)]

typedef __attribute__((ext_vector_type(8))) short bf16x8;
typedef __attribute__((ext_vector_type(4))) float f32x4;

__device__ __forceinline__ unsigned short f2b(float f) {
  unsigned int x = __builtin_bit_cast(unsigned int, f);
  unsigned int lsb = (x >> 16) & 1u;
  x += 0x7fffu + lsb;
  return (unsigned short)(x >> 16);
}

typedef __attribute__((address_space(1))) const unsigned int gas_uint;
typedef __attribute__((address_space(3))) unsigned int las_uint;
__device__ __forceinline__ void async_ld(const void* g, const void* l) {
  __builtin_amdgcn_global_load_lds((gas_uint*)(uintptr_t)g,
                                   (las_uint*)(unsigned int)(uintptr_t)l, 16, 0, 0);
}

// ---------- positional embedding fp32 [C][M] + fused per-row sums ----------
__global__ void k_pe(float* __restrict__ pe, float* __restrict__ pesum) {
  int c = blockIdx.x, m = threadIdx.x;  // 512 blocks x 1024 threads
  float freq = expf((float)(c & ~1) * (-9.210340371976184f / 512.0f));
  float ang = (float)m * freq;
  float v = (c & 1) ? cosf(ang) : sinf(ang);
  pe[c * M_N + m] = v;
  float s = v;
  for (int off = 32; off; off >>= 1) s += __shfl_down(s, off);
  __shared__ float ws[16];
  if ((m & 63) == 0) ws[m >> 6] = s;
  __syncthreads();
  if (m < 16) {
    float t = ws[m];
    for (int off = 8; off; off >>= 1) t += __shfl_down(t, off);
    if (m == 0) pesum[c] = t;
  }
}

// ---------- pass 1: fp32 row sums, atomic-free (block owns exactly 2 rows) --
__global__ void k_rs(const float* __restrict__ src, float* __restrict__ rb) {
  __shared__ float ws[4];
  int t = threadIdx.x;
  size_t e = ((size_t)blockIdx.x * 256 + t) * 8;
  const float4* s4 = (const float4*)(src + e);
  float4 v0 = s4[0], v1 = s4[1];
  float s = v0.x + v0.y + v0.z + v0.w + v1.x + v1.y + v1.z + v1.w;
  for (int off = 32; off; off >>= 1) s += __shfl_down(s, off);
  if ((t & 63) == 0) ws[t >> 6] = s;
  __syncthreads();
  if (t == 0) rb[blockIdx.x * 2] = ws[0] + ws[1];
  if (t == 128) rb[blockIdx.x * 2 + 1] = ws[2] + ws[3];
}

// ---------- gate (fp32 exact): outputs u = g*(rb+pesum), rb copy, g ----------
__global__ void k_gate(const float* __restrict__ wp, const float* __restrict__ bp,
                       const float* __restrict__ rb0, const float* __restrict__ pesum,
                       float* __restrict__ u, float* __restrict__ rbF,
                       float* __restrict__ gateF) {
  int idx = blockIdx.x * 256 + threadIdx.x;  // [0, B*C)
  int b = idx >> 9, c = idx & (C_N - 1);
  float rbv = rb0[idx];
  float rx = rbv + pesum[c];
  float acc = 0.f;
  for (int k = 0; k < 5; ++k) {
    int cc = c + k - 2;
    if (cc < 0 || cc >= C_N) continue;
    float y = (rb0[b * C_N + cc] + pesum[cc]) * (1.0f / 1024.0f);
    acc += y * wp[c * 5 + k];
  }
  float g = 1.0f / (1.0f + expf(-(acc + bp[c])));
  gateF[idx] = g;
  u[idx] = g * rx;
  rbF[idx] = rbv;
}

// ---------- pass 2: IN-PLACE fp32 row -> [H bf16 | X' bf16] -----------------
__global__ void k_x(float* __restrict__ hbase, const float* __restrict__ pe,
                    const float* __restrict__ gateF) {
  int row = blockIdx.x;  // b*512 + c
  int c = row & (C_N - 1), t = threadIdx.x;
  float* rp = hbase + (size_t)row * M_N;
  float4 h4 = ((const float4*)rp)[t];
  float4 p4 = ((const float4*)(pe + (size_t)c * M_N))[t];
  float g = gateF[row];
  union { uint2 v; unsigned short us[4]; } H, X;
  H.us[0] = f2b(h4.x); H.us[1] = f2b(h4.y); H.us[2] = f2b(h4.z); H.us[3] = f2b(h4.w);
  X.us[0] = f2b(g * (h4.x + p4.x)); X.us[1] = f2b(g * (h4.y + p4.y));
  X.us[2] = f2b(g * (h4.z + p4.z)); X.us[3] = f2b(g * (h4.w + p4.w));
  __syncthreads();  // all reads of this row complete before any write
  unsigned short* wr = (unsigned short*)rp;
  ((uint2*)wr)[t] = H.v;            // H half: shorts [0,1024)
  ((uint2*)(wr + M_N))[t] = X.v;    // X' half: shorts [1024,2048)
}

// ---------- cov: SYMMETRIC SYRK, lower-triangle tiles only ------------------
// out = (W W^T)/M - (u u^T + rb rb^T)/M^2 (+1e-8 I). 10 of 16 tiles/batch
// computed; 6 off-diagonal tiles mirrored via LDS f32 transpose (XOR swizzle).
// 3 LDS bufs (48 KiB), depth-2 prefetch, vmcnt(4) steady state, 3 blocks/CU.
__device__ __forceinline__ void cov_stage(unsigned short (*tl)[128 * 32],
                                          const unsigned short* srcp, int wsel,
                                          int ldst) {
  for (int g = 0; g < 4; g++)
    async_ld(srcp + (size_t)g * (16 * K_W), &tl[wsel][ldst + g * 512]);
}

template <int VM, bool STG, int CUR>
__device__ __forceinline__ void cov_step(
    unsigned short (*tiles)[2][128 * 32], int it, const unsigned short* srcp,
    int wsel, int ldst, int wr, int wc, int fr, int fcol, f32x4 (&acc)[4][4]) {
  asm volatile("s_waitcnt vmcnt(%0)" ::"n"(VM) : "memory");
  __builtin_amdgcn_sched_barrier(0);
  __builtin_amdgcn_s_barrier();
  __builtin_amdgcn_sched_barrier(0);
  bf16x8 bf[4], af[4];
  for (int j = 0; j < 4; j++)
    bf[j] = *(const bf16x8*)&tiles[CUR][1][(wc + j * 16 + fr) * 32 + fcol];
  for (int i = 0; i < 4; i++)
    af[i] = *(const bf16x8*)&tiles[CUR][0][(wr + i * 16 + fr) * 32 + fcol];
  if (STG)
    cov_stage(tiles[(CUR + 2) % 3], srcp + (size_t)(it + 2) * 32, wsel, ldst);
  asm volatile("s_waitcnt lgkmcnt(0)" ::: "memory");
  __builtin_amdgcn_sched_barrier(0);
  __builtin_amdgcn_s_setprio(1);
  for (int i = 0; i < 4; i++)
    for (int j = 0; j < 4; j++)
      acc[i][j] = __builtin_amdgcn_mfma_f32_16x16x32_bf16(af[i], bf[j], acc[i][j], 0, 0, 0);
  __builtin_amdgcn_s_setprio(0);
}

__global__ __launch_bounds__(256, 3)
void k_cov(const unsigned short* __restrict__ W, const float* __restrict__ aux,
           float* __restrict__ out, int b0, int bpx) {
  __shared__ unsigned short tiles[3][2][128 * 32];  // 3 bufs x (A,B) = 48 KB
  int t = threadIdx.x, lane = t & 63, w = t >> 6;
  int bid = blockIdx.x;
  int xcd = bid & 7, i5 = bid >> 3;
  int b = b0 + xcd * bpx + i5 / 10;
  int s = i5 % 10;
  int ti = (s >= 1) + (s >= 3) + (s >= 6);       // lower-triangle tile row
  int tj = s - ti * (ti + 1) / 2;                // tile col, tj <= ti
  int cblk = ti * 128, dblk = tj * 128;

  int rowbase = (w & 1) ? dblk : cblk;
  int half = w >> 1, wsel = w & 1;
  int gcol = (lane & 3) ^ ((lane >> 3) & 3);
  const unsigned short* srcp = W + (size_t)b * (C_N * K_W)
      + (size_t)(rowbase + half * 64 + (lane >> 2)) * K_W + gcol * 8;
  int ldst = half * 2048;

  int wr = (w >> 1) * 64, wc = (w & 1) * 64;
  int fr = lane & 15, kc = lane >> 4;
  int fcol = (kc ^ ((fr >> 1) & 3)) * 8;

  f32x4 acc[4][4];
  const f32x4 z = {0.f, 0.f, 0.f, 0.f};
  for (int i = 0; i < 4; i++) for (int j = 0; j < 4; j++) acc[i][j] = z;

  // prologue: stage k-steps 0,1 into bufs 0,1 (8 loads in flight)
  cov_stage(tiles[0], srcp, wsel, ldst);
  cov_stage(tiles[1], srcp + 32, wsel, ldst);

  for (int it = 0; it < 60; it += 3) {  // issues stages 2..61
    cov_step<4, true, 0>(tiles, it + 0, srcp, wsel, ldst, wr, wc, fr, fcol, acc);
    cov_step<4, true, 1>(tiles, it + 1, srcp, wsel, ldst, wr, wc, fr, fcol, acc);
    cov_step<4, true, 2>(tiles, it + 2, srcp, wsel, ldst, wr, wc, fr, fcol, acc);
  }
  cov_step<4, true, 0>(tiles, 60, srcp, wsel, ldst, wr, wc, fr, fcol, acc);   // stg 62
  cov_step<4, true, 1>(tiles, 61, srcp, wsel, ldst, wr, wc, fr, fcol, acc);   // stg 63
  cov_step<4, false, 2>(tiles, 62, srcp, wsel, ldst, wr, wc, fr, fcol, acc);
  cov_step<0, false, 0>(tiles, 63, srcp, wsel, ldst, wr, wc, fr, fcol, acc);

  const float invM = 1.0f / 1024.0f, invM2 = invM * invM;
  const float* ub = aux + (size_t)b * C_N;
  const float* rbb = aux + (size_t)B_N * C_N + (size_t)b * C_N;
  // direct write of the computed (lower) tile
  for (int i = 0; i < 4; i++)
    for (int r = 0; r < 4; r++) {
      int c = cblk + wr + i * 16 + kc * 4 + r;
      float uc = ub[c], rbc = rbb[c];
      for (int j = 0; j < 4; j++) {
        int d = dblk + wc + j * 16 + fr;
        float v = acc[i][j][r] * invM - (uc * ub[d] + rbc * rbb[d]) * invM2;
        if (c == d) v += 1e-8f;
        out[((size_t)b * C_N + c) * C_N + d] = v;
      }
    }

  // mirror write for off-diagonal tiles: LDS f32 transpose in two 64-col halves
  if (ti != tj) {
    float* tb = (float*)tiles;  // [64][128] f32 = 32 KiB (fits 48 KiB)
    for (int hp = 0; hp < 2; ++hp) {
      __syncthreads();  // main-loop reads / previous half's reads complete
      if ((w >> 1) == hp) {
        for (int i = 0; i < 4; i++)
          for (int j = 0; j < 4; j++)
            for (int r = 0; r < 4; r++) {
              int ch = i * 16 + kc * 4 + r;      // half-local c in [0,64)
              int dl = wc + j * 16 + fr;         // local d in [0,128)
              tb[ch * 128 + (dl ^ (ch & 31))] = acc[i][j][r];
            }
      }
      __syncthreads();
      for (int p = 0; p < 8; ++p) {
        int dl = p * 16 + (t >> 4);
        int cl = (t & 15) * 4;
        int dg = dblk + dl;
        float ud = ub[dg], rbd = rbb[dg];
        float4 o;
        float* op = (float*)&o;
        for (int q = 0; q < 4; ++q) {
          int cg = cblk + hp * 64 + cl + q;
          float raw = tb[(cl + q) * 128 + (dl ^ ((cl + q) & 31))];
          op[q] = raw * invM - (ub[cg] * ud + rbb[cg] * rbd) * invM2;
        }
        *(float4*)&out[((size_t)b * C_N + dg) * C_N + (cblk + hp * 64 + cl)] = o;
      }
    }
  }
}

extern "C" void kernel_launch(void* const* d_in, const int* in_sizes, int n_in,
                              void* d_out, int out_size, void* d_ws, size_t ws_size,
                              hipStream_t stream) {
  const float* h32 = (const float*)d_in[0];
  const float* conv_w = (const float*)d_in[1];
  const float* conv_b = (const float*)d_in[2];
  char* OUT = (char*)d_out;   // 64 MiB output
  char* HIN = (char*)d_in[0]; // 128 MiB input; becomes W in-place (harness restores)

  // pre-cov scratch in OUT tail (all consumed before cov writes everything)
  char* SCR = OUT + (48ull << 20);
  float* rb0   = (float*)SCR;                   // 128 KiB
  float* pesum = (float*)(SCR + (128 << 10));   // 2 KiB
  float* gateF = (float*)(SCR + (192 << 10));   // 128 KiB
  float* peF   = (float*)(OUT + (49ull << 20)); // 2 MiB fp32 pe table

  // aux (u, rb) must survive INTO cov: prefer d_ws (cov writes all of OUT)
  bool ws_ok = (d_ws != nullptr) && (ws_size >= (size_t)(256 << 10));
  float* uX = ws_ok ? (float*)d_ws : (float*)(SCR + (512 << 10));
  // layout: [0,32768) = u, [32768,65536) = rb  (contiguous 256 KiB)

  k_pe<<<C_N, 1024, 0, stream>>>(peF, pesum);
  k_rs<<<16384, 256, 0, stream>>>(h32, rb0);
  k_gate<<<(B_N * C_N) / 256, 256, 0, stream>>>(conv_w, conv_b, rb0, pesum,
                                                uX, uX + B_N * C_N, gateF);
  k_x<<<B_N * C_N, 256, 0, stream>>>((float*)HIN, peF, gateF);

  if (ws_ok) {
    // single launch: 640 = 8 XCD x (8 batches x 10 triangle tiles)
    k_cov<<<640, 256, 0, stream>>>((const unsigned short*)HIN, uX,
                                   (float*)d_out, 0, 8);
  } else {
    // fallback: two launches; aux lives in OUT+48.5MiB for L1, then moves to
    // dead W(b=0) region in HIN for L2.
    k_cov<<<320, 256, 0, stream>>>((const unsigned short*)HIN, uX,
                                   (float*)d_out, 0, 4);
    hipMemcpyAsync(HIN, uX, 256 << 10, hipMemcpyDeviceToDevice, stream);
    k_cov<<<320, 256, 0, stream>>>((const unsigned short*)HIN, (const float*)HIN,
                                   (float*)d_out, 32, 4);
  }
}